// Round 2
// baseline (126816.138 us; speedup 1.0000x reference)
//
#include <hip/hip_runtime.h>

// RNNDetector: 2-layer LSTM (H=64), T=262144 sequential steps + 16-wide head.
// ROUND 12: R11 (block-pipelined, 1 barrier/32 steps) = 117.5ms, ~1076cyc/step
// vs ~480cyc per-wave serial floor. Remaining gap: 3 waves share ONE CU's LDS
// pipe (~22 ds_read_b128/step) and each recurrence's write->read turnaround
// queues behind the other waves' bursts. THIS ROUND: one CU per serial chain.
//   WG0: L0 recurrence wave (R11 body, untouched) + helper wave exporting h0
//        blocks to a global ring (agent-scope atomics) with backpressure.
//   WG1: 2 waves; stage h0/h1 to LDS, compute xp1 = Wih1*h0+b (parallel, 16
//        steps/wave -> finishes in ~tau/3, never gates) + head; publish xp.
//   WG2: L1 recurrence wave (R11 body; xp from LDS dbuf) + helper wave that
//        stages xp global->LDS and exports h1 blocks.
// Cross-CU: relaxed agent atomics for data (XCD-coherence-safe), acq/rel
// counters for flags - 1 flag/32 steps, NEVER on a recurrence wave. Rings:
// h0/h1 16KB each (8 blk), xp 128KB (4 blk) in d_ws; all L2/LLC-resident.
// Cooperative launch guarantees the 3 WGs are co-resident.

constexpr int T  = 262144;
constexpr int B  = 32;          // steps per block
constexpr int NB = T / B;       // 8192 blocks

// ws layout (dword offsets): weights [0,25088) as in R11.
constexpr int H0G = 25600;  constexpr int H0_RING = 8;   // 8 x 1024 dwords
constexpr int H1G = 33792;  constexpr int H1_RING = 8;   // 8 x 1024 dwords
constexpr int XPG = 41984;  constexpr int XP_RING = 4;   // 4 x 8192 dwords
constexpr int CNT = 74752;  // counters: [0]=c_h0 [1]=c_xp [2]=c_h1 [3]=c_head

typedef _Float16 h2v __attribute__((ext_vector_type(2)));
typedef unsigned u4 __attribute__((ext_vector_type(4)));

__device__ __forceinline__ float rcp_f(float x) { return __builtin_amdgcn_rcpf(x); }

#define BARRIER() asm volatile("s_waitcnt lgkmcnt(0)\n\ts_barrier" ::: "memory")

static __device__ __forceinline__ float fd(unsigned w, unsigned h, float acc) {
#if __has_builtin(__builtin_amdgcn_fdot2)
  return __builtin_amdgcn_fdot2(__builtin_bit_cast(h2v, w),
                                __builtin_bit_cast(h2v, h), acc, false);
#else
  h2v a = __builtin_bit_cast(h2v, w), b = __builtin_bit_cast(h2v, h);
  acc = fmaf((float)a.x, (float)b.x, acc);
  acc = fmaf((float)a.y, (float)b.y, acc);
  return acc;
#endif
}

#define DP4(acc, W, H) { acc = fd((W).x, (H).x, acc); acc = fd((W).y, (H).y, acc); \
                         acc = fd((W).z, (H).z, acc); acc = fd((W).w, (H).w, acc); }

#define DPPX1(x) __builtin_bit_cast(float, __builtin_amdgcn_mov_dpp(            \
                    __builtin_bit_cast(int, (x)), 0xB1, 0xF, 0xF, true))
#define DPPX2(x) __builtin_bit_cast(float, __builtin_amdgcn_mov_dpp(            \
                    __builtin_bit_cast(int, (x)), 0x4E, 0xF, 0xF, true))

__device__ __forceinline__ float sigf(float x) {
  float z = fminf(fmaxf(x, -30.f), 30.f);
  return rcp_f(1.f + __expf(-z));
}
__device__ __forceinline__ float tanhf_(float x) {
  float z = fminf(fmaxf(x, -15.f), 15.f);
  float e2 = __expf(-2.f * z);
  return (1.f - e2) * rcp_f(1.f + e2);
}

// ---- agent-scope (cross-XCD-safe) atomics ----
__device__ __forceinline__ void ag_store(unsigned* p, unsigned v) {
  __hip_atomic_store(p, v, __ATOMIC_RELAXED, __HIP_MEMORY_SCOPE_AGENT);
}
__device__ __forceinline__ unsigned ag_load(const unsigned* p) {
  return __hip_atomic_load(p, __ATOMIC_RELAXED, __HIP_MEMORY_SCOPE_AGENT);
}
__device__ __forceinline__ void flag_set(int* p, int v) {
  __hip_atomic_store(p, v, __ATOMIC_RELEASE, __HIP_MEMORY_SCOPE_AGENT);
}
__device__ __forceinline__ void waitge(int* p, int tgt) {
  while (__hip_atomic_load(p, __ATOMIC_ACQUIRE, __HIP_MEMORY_SCOPE_AGENT) < tgt)
    __builtin_amdgcn_s_sleep(8);
}

// f32 -> f16 RNE
__device__ unsigned f16rne(float f) {
  unsigned u = __float_as_uint(f);
  unsigned s = (u >> 16) & 0x8000u;
  int e = (int)((u >> 23) & 0xff) - 127;
  unsigned m = u & 0x7fffffu;
  if (e < -14) return s;
  unsigned h = s | (unsigned)((e + 15) << 10) | (m >> 13);
  unsigned rem = m & 0x1fffu;
  h += (rem > 0x1000u) || (rem == 0x1000u && (h & 1u));
  return h;
}

// ---- prepass: pack f16 weights (layout unchanged from R11) + zero counters --
// region A [0,8192): Whh0 (L0 rec); B [8192,16384): Whh1 (L1 rec);
// C [16384,24576): Wih1 (xp); E [24576,25088): head Wlin.
__global__ void pack_w(const float* __restrict__ Whh0,
                       const float* __restrict__ Whh1,
                       const float* __restrict__ Wih1,
                       const float* __restrict__ Wlin,
                       unsigned* __restrict__ ws) {
  if (blockIdx.x == 0 && threadIdx.x < 4) ws[CNT + threadIdx.x] = 0u;
  int i = blockIdx.x * 256 + threadIdx.x;
  if (i >= 25088) return;
  float v0, v1;
  if (i < 24576) {
    int w = i >> 13, rem = i & 8191, l = rem >> 7, d = rem & 127;
    int r = d >> 5, kp = d & 31, row = r * 64 + l;
    const float* src = (w == 0) ? Whh0 : (w == 1) ? Whh1 : Wih1;
    v0 = src[row * 64 + 2 * kp]; v1 = src[row * 64 + 2 * kp + 1];
  } else {
    int j = i - 24576, l = j >> 3, d = j & 7;
    int m = l >> 2, kq = l & 3, k = kq * 16 + 2 * d;
    v0 = Wlin[m * 64 + k]; v1 = Wlin[m * 64 + k + 1];
  }
  ws[i] = f16rne(v0) | (f16rne(v1) << 16);
}

#define DECLW32(wp)                                                            \
  u4 W0=(wp)[0],  W1=(wp)[1],  W2=(wp)[2],  W3=(wp)[3],                        \
     W4=(wp)[4],  W5=(wp)[5],  W6=(wp)[6],  W7=(wp)[7],                        \
     W8=(wp)[8],  W9=(wp)[9],  W10=(wp)[10],W11=(wp)[11],                      \
     W12=(wp)[12],W13=(wp)[13],W14=(wp)[14],W15=(wp)[15],                      \
     W16=(wp)[16],W17=(wp)[17],W18=(wp)[18],W19=(wp)[19],                      \
     W20=(wp)[20],W21=(wp)[21],W22=(wp)[22],W23=(wp)[23],                      \
     W24=(wp)[24],W25=(wp)[25],W26=(wp)[26],W27=(wp)[27],                      \
     W28=(wp)[28],W29=(wp)[29],W30=(wp)[30],W31=(wp)[31]

#define PINW8(a,b,c,d,e,f,g,h)                                                 \
  asm volatile("" : "+v"(a), "+v"(b), "+v"(c), "+v"(d),                        \
                    "+v"(e), "+v"(f), "+v"(g), "+v"(h))
#define PINALL() { PINW8(W0,W1,W2,W3,W4,W5,W6,W7);                             \
                   PINW8(W8,W9,W10,W11,W12,W13,W14,W15);                       \
                   PINW8(W16,W17,W18,W19,W20,W21,W22,W23);                     \
                   PINW8(W24,W25,W26,W27,W28,W29,W30,W31); }

__global__ __launch_bounds__(128)
__attribute__((amdgpu_waves_per_eu(1, 1)))
void rnn_fused(
    const float* __restrict__ y,
    const float* __restrict__ Wih0, const float* __restrict__ bih0,
    const float* __restrict__ bhh0,
    const float* __restrict__ bih1, const float* __restrict__ bhh1,
    const float* __restrict__ blin,
    unsigned* __restrict__ wsu,
    float* __restrict__ out)
{
  const int tid  = threadIdx.x;
  const int role = blockIdx.x;
  int* cnt = (int*)(wsu + CNT);

  // role0: [0,2048) h0 local ring (64 slots x 32 dwords)
  // role1: [0,1024) staged h0 blk ; [1024,2048) staged h1 blk
  // role2: [0,2048) h1 local ring ; [2048,18432) xp double-buffer (2 x 8192)
  __shared__ __align__(16) unsigned smem[18432];
  for (int j = tid; j < 2048; j += 128) smem[j] = 0u;
  __syncthreads();

  if (role == 0) {
    // ==================== WG0: layer-0 recurrence + h0 export ===============
    if (tid < 64) {
      const int e = tid;
      const u4* wp = (const u4*)(wsu + e * 128);
      DECLW32(wp);
      float bbi = bih0[e] + bhh0[e];
      float bbf = bih0[64 + e] + bhh0[64 + e];
      float bbg = bih0[128 + e] + bhh0[128 + e];
      float bbo = bih0[192 + e] + bhh0[192 + e];
      float wii = Wih0[e], wif = Wih0[64 + e], wig = Wih0[128 + e], wio = Wih0[192 + e];
      float c0 = 0.f;
      float ylv = y[e & (B - 1)];
      for (int k = 0; k < NB; ++k) {
        float yln = (k + 1 < NB) ? y[(k + 1) * B + (e & (B - 1))] : 0.f;
        #pragma unroll 1
        for (int i = 0; i < B; ++i) {
          const int s = k * B + i;
          PINALL();
          const u4* hp = (const u4*)(smem + ((s - 1) & 63) * 32);
          u4 H0=hp[0],H1=hp[1],H2=hp[2],H3=hp[3],H4=hp[4],H5=hp[5],H6=hp[6],H7=hp[7];
          float ys = __builtin_bit_cast(float,
              __builtin_amdgcn_readlane(__builtin_bit_cast(int, ylv), i));
          float ai0=0,ai1=0, af0=0,af1=0, ag0=0,ag1=0, ao0=0,ao1=0;
          DP4(ai0,W0,H0)  DP4(af0,W8,H0)  DP4(ag0,W16,H0) DP4(ao0,W24,H0)
          DP4(ai1,W1,H1)  DP4(af1,W9,H1)  DP4(ag1,W17,H1) DP4(ao1,W25,H1)
          DP4(ai0,W2,H2)  DP4(af0,W10,H2) DP4(ag0,W18,H2) DP4(ao0,W26,H2)
          DP4(ai1,W3,H3)  DP4(af1,W11,H3) DP4(ag1,W19,H3) DP4(ao1,W27,H3)
          DP4(ai0,W4,H4)  DP4(af0,W12,H4) DP4(ag0,W20,H4) DP4(ao0,W28,H4)
          DP4(ai1,W5,H5)  DP4(af1,W13,H5) DP4(ag1,W21,H5) DP4(ao1,W29,H5)
          DP4(ai0,W6,H6)  DP4(af0,W14,H6) DP4(ag0,W22,H6) DP4(ao0,W30,H6)
          DP4(ai1,W7,H7)  DP4(af1,W15,H7) DP4(ag1,W23,H7) DP4(ao1,W31,H7)
          float I = sigf((ai0 + ai1) + fmaf(ys, wii, bbi));
          float F = sigf((af0 + af1) + fmaf(ys, wif, bbf));
          float G = tanhf_((ag0 + ag1) + fmaf(ys, wig, bbg));
          float O = sigf((ao0 + ao1) + fmaf(ys, wio, bbo));
          c0 = fmaf(F, c0, I * G);
          float h = O * tanhf_(c0);
          float hp1 = DPPX1(h);
          unsigned pk = __builtin_bit_cast(unsigned, __builtin_amdgcn_cvt_pkrtz(h, hp1));
          if (!(e & 1)) smem[(s & 63) * 32 + (e >> 1)] = pk;
        }
        ylv = yln;
        BARRIER();
      }
      BARRIER();
    } else {
      const int l = tid - 64;
      auto export_h0 = [&](int kb) {
        if (kb >= H0_RING) waitge(cnt + 1, kb - H0_RING + 1);   // c_xp consumed
        const u4* src = (const u4*)(smem + (kb & 1) * 1024 + l * 16);
        u4 A0 = src[0], A1 = src[1], A2 = src[2], A3 = src[3];
        unsigned* dst = wsu + H0G + (kb & (H0_RING - 1)) * 1024 + l * 16;
        ag_store(dst + 0,  A0.x); ag_store(dst + 1,  A0.y);
        ag_store(dst + 2,  A0.z); ag_store(dst + 3,  A0.w);
        ag_store(dst + 4,  A1.x); ag_store(dst + 5,  A1.y);
        ag_store(dst + 6,  A1.z); ag_store(dst + 7,  A1.w);
        ag_store(dst + 8,  A2.x); ag_store(dst + 9,  A2.y);
        ag_store(dst + 10, A2.z); ag_store(dst + 11, A2.w);
        ag_store(dst + 12, A3.x); ag_store(dst + 13, A3.y);
        ag_store(dst + 14, A3.z); ag_store(dst + 15, A3.w);
        __threadfence();
        if (l == 0) flag_set(cnt + 0, kb + 1);
      };
      for (int k = 0; k < NB; ++k) {
        if (k >= 1) export_h0(k - 1);
        BARRIER();
      }
      export_h0(NB - 1);
      BARRIER();
    }
  } else if (role == 1) {
    // ============ WG1: xp producer (block j) + head (block j-2) =============
    const int w = tid >> 6, e = tid & 63;
    const u4* wp = (const u4*)(wsu + 16384 + e * 128);
    DECLW32(wp);
    const u4* hwp = (const u4*)(wsu + 24576 + e * 8);
    u4 HW0 = hwp[0], HW1 = hwp[1];
    float bb0 = bih1[e] + bhh1[e];
    float bb1 = bih1[64 + e] + bhh1[64 + e];
    float bb2 = bih1[128 + e] + bhh1[128 + e];
    float bb3 = bih1[192 + e] + bhh1[192 + e];
    const int m = e >> 2, kq = e & 3;
    float bl = (kq == 0) ? blin[m] : 0.f;

    for (int j = 0; j < NB + 2; ++j) {
      if (j < NB) {                                  // stage h0(j)
        waitge(cnt + 0, j + 1);
        const unsigned* g = wsu + H0G + (j & (H0_RING - 1)) * 1024 + tid * 8;
        unsigned d0 = ag_load(g + 0), d1 = ag_load(g + 1), d2 = ag_load(g + 2), d3 = ag_load(g + 3);
        unsigned d4 = ag_load(g + 4), d5 = ag_load(g + 5), d6 = ag_load(g + 6), d7 = ag_load(g + 7);
        u4 P0 = {d0, d1, d2, d3}, P1 = {d4, d5, d6, d7};
        *(u4*)(smem + tid * 8) = P0;
        *(u4*)(smem + tid * 8 + 4) = P1;
      }
      if (j >= 2) {                                  // stage h1(j-2)
        waitge(cnt + 2, j - 1);
        const unsigned* g = wsu + H1G + ((j - 2) & (H1_RING - 1)) * 1024 + tid * 8;
        unsigned d0 = ag_load(g + 0), d1 = ag_load(g + 1), d2 = ag_load(g + 2), d3 = ag_load(g + 3);
        unsigned d4 = ag_load(g + 4), d5 = ag_load(g + 5), d6 = ag_load(g + 6), d7 = ag_load(g + 7);
        u4 P0 = {d0, d1, d2, d3}, P1 = {d4, d5, d6, d7};
        *(u4*)(smem + 1024 + tid * 8) = P0;
        *(u4*)(smem + 1024 + tid * 8 + 4) = P1;
      }
      __syncthreads();
      if (j < NB) {                                  // xp1 for block j
        unsigned* xq0 = wsu + XPG + (j & (XP_RING - 1)) * 8192;
        #pragma unroll 1
        for (int i = w * 16; i < w * 16 + 16; ++i) {
          PINALL();
          const u4* hp = (const u4*)(smem + i * 32);
          u4 H0=hp[0],H1=hp[1],H2=hp[2],H3=hp[3],H4=hp[4],H5=hp[5],H6=hp[6],H7=hp[7];
          float p0a=0,p0b=0, p1a=0,p1b=0, p2a=0,p2b=0, p3a=0,p3b=0;
          DP4(p0a,W0,H0) DP4(p1a,W8,H0)  DP4(p2a,W16,H0) DP4(p3a,W24,H0)
          DP4(p0b,W1,H1) DP4(p1b,W9,H1)  DP4(p2b,W17,H1) DP4(p3b,W25,H1)
          DP4(p0a,W2,H2) DP4(p1a,W10,H2) DP4(p2a,W18,H2) DP4(p3a,W26,H2)
          DP4(p0b,W3,H3) DP4(p1b,W11,H3) DP4(p2b,W19,H3) DP4(p3b,W27,H3)
          DP4(p0a,W4,H4) DP4(p1a,W12,H4) DP4(p2a,W20,H4) DP4(p3a,W28,H4)
          DP4(p0b,W5,H5) DP4(p1b,W13,H5) DP4(p2b,W21,H5) DP4(p3b,W29,H5)
          DP4(p0a,W6,H6) DP4(p1a,W14,H6) DP4(p2a,W22,H6) DP4(p3a,W30,H6)
          DP4(p0b,W7,H7) DP4(p1b,W15,H7) DP4(p2b,W23,H7) DP4(p3b,W31,H7)
          unsigned* xq = xq0 + i * 256;
          ag_store(xq + e,       __float_as_uint((p0a + p0b) + bb0));
          ag_store(xq + 64 + e,  __float_as_uint((p1a + p1b) + bb1));
          ag_store(xq + 128 + e, __float_as_uint((p2a + p2b) + bb2));
          ag_store(xq + 192 + e, __float_as_uint((p3a + p3b) + bb3));
        }
      }
      if (j >= 2) {                                  // head for block j-2
        const int tb = (j - 2) * B;
        #pragma unroll 1
        for (int i = w * 16; i < w * 16 + 16; ++i) {
          const u4* h1p = (const u4*)(smem + 1024 + i * 32 + kq * 8);
          u4 X0 = h1p[0], X1 = h1p[1];
          float r2 = 0.f;
          DP4(r2, HW0, X0) DP4(r2, HW1, X1)
          r2 += DPPX1(r2);
          r2 += DPPX2(r2);
          if (kq == 0) out[(tb + i) * 16 + m] = r2 + bl;
        }
      }
      __threadfence();
      __syncthreads();
      if (tid == 0 && j < NB) flag_set(cnt + 1, j + 1);    // c_xp
      if (tid == 64 && j >= 2) flag_set(cnt + 3, j - 1);   // c_head
    }
  } else {
    // ========== WG2: layer-1 recurrence + xp staging + h1 export ============
    if (tid < 64) {
      const int e = tid;
      const u4* wp = (const u4*)(wsu + 8192 + e * 128);
      DECLW32(wp);
      float c1 = 0.f;
      BARRIER();                                     // xp(0) staged
      for (int k = 0; k < NB; ++k) {
        const float* xqb = (const float*)(smem + 2048 + (k & 1) * 8192);
        #pragma unroll 1
        for (int i = 0; i < B; ++i) {
          const int t = k * B + i;
          PINALL();
          const u4* hp = (const u4*)(smem + ((t - 1) & 63) * 32);
          u4 H0=hp[0],H1=hp[1],H2=hp[2],H3=hp[3],H4=hp[4],H5=hp[5],H6=hp[6],H7=hp[7];
          float ai0=0,ai1=0, af0=0,af1=0, ag0=0,ag1=0, ao0=0,ao1=0;
          DP4(ai0,W0,H0)  DP4(af0,W8,H0)  DP4(ag0,W16,H0) DP4(ao0,W24,H0)
          DP4(ai1,W1,H1)  DP4(af1,W9,H1)  DP4(ag1,W17,H1) DP4(ao1,W25,H1)
          DP4(ai0,W2,H2)  DP4(af0,W10,H2) DP4(ag0,W18,H2) DP4(ao0,W26,H2)
          DP4(ai1,W3,H3)  DP4(af1,W11,H3) DP4(ag1,W19,H3) DP4(ao1,W27,H3)
          DP4(ai0,W4,H4)  DP4(af0,W12,H4) DP4(ag0,W20,H4) DP4(ao0,W28,H4)
          DP4(ai1,W5,H5)  DP4(af1,W13,H5) DP4(ag1,W21,H5) DP4(ao1,W29,H5)
          DP4(ai0,W6,H6)  DP4(af0,W14,H6) DP4(ag0,W22,H6) DP4(ao0,W30,H6)
          DP4(ai1,W7,H7)  DP4(af1,W15,H7) DP4(ag1,W23,H7) DP4(ao1,W31,H7)
          const float* xq = xqb + i * 256;
          float xi = xq[e], xf = xq[64 + e], xg = xq[128 + e], xo = xq[192 + e];
          float I = sigf(xi + (ai0 + ai1));
          float F = sigf(xf + (af0 + af1));
          float G = tanhf_(xg + (ag0 + ag1));
          float O = sigf(xo + (ao0 + ao1));
          c1 = fmaf(F, c1, I * G);
          float h = O * tanhf_(c1);
          float hp1 = DPPX1(h);
          unsigned pk = __builtin_bit_cast(unsigned, __builtin_amdgcn_cvt_pkrtz(h, hp1));
          if (!(e & 1)) smem[(t & 63) * 32 + (e >> 1)] = pk;
        }
        BARRIER();
      }
      BARRIER();
    } else {
      const int l = tid - 64;
      auto stage_xp = [&](int blk) {
        const unsigned* g = wsu + XPG + (blk & (XP_RING - 1)) * 8192 + l * 128;
        unsigned* d = smem + 2048 + (blk & 1) * 8192 + l * 128;
        #pragma unroll 1
        for (int c0 = 0; c0 < 32; c0 += 8) {
          u4 P[8];
          #pragma unroll
          for (int q = 0; q < 8; ++q) {
            P[q].x = ag_load(g + (c0 + q) * 4 + 0);
            P[q].y = ag_load(g + (c0 + q) * 4 + 1);
            P[q].z = ag_load(g + (c0 + q) * 4 + 2);
            P[q].w = ag_load(g + (c0 + q) * 4 + 3);
          }
          #pragma unroll
          for (int q = 0; q < 8; ++q) *(u4*)(d + (c0 + q) * 4) = P[q];
        }
      };
      auto export_h1 = [&](int kb, int cval) {
        if (kb >= H1_RING) waitge(cnt + 3, kb - H1_RING + 1);  // c_head consumed
        const u4* src = (const u4*)(smem + (kb & 1) * 1024 + l * 16);
        u4 A0 = src[0], A1 = src[1], A2 = src[2], A3 = src[3];
        unsigned* dst = wsu + H1G + (kb & (H1_RING - 1)) * 1024 + l * 16;
        ag_store(dst + 0,  A0.x); ag_store(dst + 1,  A0.y);
        ag_store(dst + 2,  A0.z); ag_store(dst + 3,  A0.w);
        ag_store(dst + 4,  A1.x); ag_store(dst + 5,  A1.y);
        ag_store(dst + 6,  A1.z); ag_store(dst + 7,  A1.w);
        ag_store(dst + 8,  A2.x); ag_store(dst + 9,  A2.y);
        ag_store(dst + 10, A2.z); ag_store(dst + 11, A2.w);
        ag_store(dst + 12, A3.x); ag_store(dst + 13, A3.y);
        ag_store(dst + 14, A3.z); ag_store(dst + 15, A3.w);
        __threadfence();
        if (l == 0) flag_set(cnt + 2, cval);
      };
      waitge(cnt + 1, 1);                            // xp(0) published
      stage_xp(0);
      BARRIER();
      for (int k = 0; k < NB; ++k) {
        if (k >= 1) export_h1(k - 1, k);
        if (k + 1 < NB) {
          waitge(cnt + 1, k + 2);
          stage_xp(k + 1);
        }
        BARRIER();
      }
      export_h1(NB - 1, NB);
      BARRIER();
    }
  }
}

extern "C" void kernel_launch(void* const* d_in, const int* in_sizes, int n_in,
                              void* d_out, int out_size, void* d_ws, size_t ws_size,
                              hipStream_t stream) {
  const float* y    = (const float*)d_in[0];
  const float* Wih0 = (const float*)d_in[1];
  const float* Whh0 = (const float*)d_in[2];
  const float* bih0 = (const float*)d_in[3];
  const float* bhh0 = (const float*)d_in[4];
  const float* Wih1 = (const float*)d_in[5];
  const float* Whh1 = (const float*)d_in[6];
  const float* bih1 = (const float*)d_in[7];
  const float* bhh1 = (const float*)d_in[8];
  const float* Wlin = (const float*)d_in[9];
  const float* blin = (const float*)d_in[10];
  unsigned* ws = (unsigned*)d_ws;                // ~300 KB used
  float* outp = (float*)d_out;

  pack_w<<<dim3(98), dim3(256), 0, stream>>>(Whh0, Whh1, Wih1, Wlin, ws);

  void* args[] = {(void*)&y, (void*)&Wih0, (void*)&bih0, (void*)&bhh0,
                  (void*)&bih1, (void*)&bhh1, (void*)&blin, (void*)&ws,
                  (void*)&outp};
  hipLaunchCooperativeKernel((void*)rnn_fused, dim3(3), dim3(128), args, 0, stream);
}

// Round 3
// 114781.384 us; speedup vs baseline: 1.1048x; 1.1048x over previous
//
#include <hip/hip_runtime.h>

// RNNDetector: 2-layer LSTM (H=64), T=262144 sequential steps + 16-wide head.
// ROUND 13: revert R12 (3-CU split regressed: 16M LDS bank conflicts in xp
// staging, 1GB HBM coherence traffic from per-dword agent atomics). Base =
// R11 single-CU block-pipeline (117.5ms, ~1076cyc/step), which is ISSUE +
// LATENCY bound on each recurrence SIMD (~400cyc raw issue + ~70 trans
// penalty + ~150 LDS turnaround + chain bubbles). This round shrinks issue
// count + serial chain, no structural change:
//  - exp2-prescale: weights/biases carry log2e (2*log2e for gate g) so
//    sigmoid = rcp(1+exp2(-u)), tanh = (1-e2)*rcp(1+e2); clamps replaced by
//    a single overflow guard (positive side saturates naturally).
//  - h written as f16 directly by all 64 lanes (ds_write_b16): kills the
//    DPP-partner + cvt_pkrtz + predicated-write tail.
//  - xp exchanged as one float4 b128 per step each way (was 4+4 b32).
//  - xq/ys hoisted ahead of H reads; s_setprio(1) on recurrence waves.

constexpr int T  = 262144;
constexpr int B  = 32;          // steps per superstep
constexpr int NB = T / B;       // 8192 blocks
constexpr int RS = 2 * B;       // 64 ring slots (2 blocks)
constexpr int K_SS = NB + 3;    // supersteps incl. pipeline drain

typedef _Float16 h2v __attribute__((ext_vector_type(2)));
typedef unsigned u4 __attribute__((ext_vector_type(4)));
typedef float    f4 __attribute__((ext_vector_type(4)));

__device__ __forceinline__ float rcp_f(float x) { return __builtin_amdgcn_rcpf(x); }

#define BARRIER() asm volatile("s_waitcnt lgkmcnt(0)\n\ts_barrier" ::: "memory")

// packed-f16 dot2: acc += w.lo*h.lo + w.hi*h.hi (f32 accumulate)
static __device__ __forceinline__ float fd(unsigned w, unsigned h, float acc) {
#if __has_builtin(__builtin_amdgcn_fdot2)
  return __builtin_amdgcn_fdot2(__builtin_bit_cast(h2v, w),
                                __builtin_bit_cast(h2v, h), acc, false);
#else
  h2v a = __builtin_bit_cast(h2v, w), b = __builtin_bit_cast(h2v, h);
  acc = fmaf((float)a.x, (float)b.x, acc);
  acc = fmaf((float)a.y, (float)b.y, acc);
  return acc;
#endif
}

#define DP4(acc, W, H) { acc = fd((W).x, (H).x, acc); acc = fd((W).y, (H).y, acc); \
                         acc = fd((W).z, (H).z, acc); acc = fd((W).w, (H).w, acc); }

// quad_perm DPP cross-lane (pure VALU, no LDS): xor1 = 0xB1, xor2 = 0x4E
#define DPPX1(x) __builtin_bit_cast(float, __builtin_amdgcn_mov_dpp(            \
                    __builtin_bit_cast(int, (x)), 0xB1, 0xF, 0xF, true))
#define DPPX2(x) __builtin_bit_cast(float, __builtin_amdgcn_mov_dpp(            \
                    __builtin_bit_cast(int, (x)), 0x4E, 0xF, 0xF, true))

// raw v_exp_f32 (2^x). gfx9-lineage: VALU->VALU interlocked, safe as asm.
__device__ __forceinline__ float exp2_f(float x) {
  float r; asm("v_exp_f32 %0, %1" : "=v"(r) : "v"(x)); return r;
}
// exp2(-u), guarded against +overflow (u <= -126 -> cap; u >> 0 underflows to 0)
__device__ __forceinline__ float exp2n_g(float u) {
  return exp2_f(fminf(-u, 126.f));
}
// u = log2e * x  ->  sigmoid(x)
__device__ __forceinline__ float sig_u(float u) {
  return rcp_f(1.f + exp2n_g(u));
}
// u = 2*log2e * z  ->  tanh(z)
__device__ __forceinline__ float tanh_u(float u) {
  float e2 = exp2n_g(u);
  return (1.f - e2) * rcp_f(1.f + e2);
}
// real-unit tanh (for cell state)
__device__ __forceinline__ float tanh_c(float c) {
  return tanh_u(c * 2.8853900817779268f);
}

constexpr float L2E  = 1.4426950408889634f;
constexpr float L2E2 = 2.8853900817779268f;

// f32 -> f16 RNE (|w| < ~2 after prescale: no overflow; flush sub-6e-5 to 0)
__device__ unsigned f16rne(float f) {
  unsigned u = __float_as_uint(f);
  unsigned s = (u >> 16) & 0x8000u;
  int e = (int)((u >> 23) & 0xff) - 127;
  unsigned m = u & 0x7fffffu;
  if (e < -14) return s;
  unsigned h = s | (unsigned)((e + 15) << 10) | (m >> 13);
  unsigned rem = m & 0x1fffu;
  h += (rem > 0x1000u) || (rem == 0x1000u && (h & 1u));
  return h;
}

// ---- prepass: pack f16 weights, per-(wave,lane)-contiguous, exp2-prescaled --
// All three 256x64 matrices share one layout: lane l, dword d (0..127):
//   r = d>>5 (gate i/f/g/o), kp = d&31, row = r*64+l, cols (2kp, 2kp+1).
//   scale = 2*log2e for gate g (r==2), log2e otherwise.
// region A [    0, 8192): Whh0  (wave0)
// region B [ 8192,16384): Whh1  (wave2)
// region C [16384,24576): Wih1  (wave1)
// region E [24576,25088): head: lane l (m=l>>2,kq=l&3), d=0..7:
//   Wlin[m][kq*16+2d], +1  (unscaled)
__global__ void pack_w(const float* __restrict__ Whh0,
                       const float* __restrict__ Whh1,
                       const float* __restrict__ Wih1,
                       const float* __restrict__ Wlin,
                       unsigned* __restrict__ ws) {
  int i = blockIdx.x * 256 + threadIdx.x;
  if (i >= 25088) return;
  float v0, v1, sc = 1.f;
  if (i < 24576) {
    int w = i >> 13, rem = i & 8191, l = rem >> 7, d = rem & 127;
    int r = d >> 5, kp = d & 31, row = r * 64 + l;
    const float* src = (w == 0) ? Whh0 : (w == 1) ? Whh1 : Wih1;
    v0 = src[row * 64 + 2 * kp]; v1 = src[row * 64 + 2 * kp + 1];
    sc = (r == 2) ? L2E2 : L2E;
  } else {
    int j = i - 24576, l = j >> 3, d = j & 7;
    int m = l >> 2, kq = l & 3, k = kq * 16 + 2 * d;
    v0 = Wlin[m * 64 + k]; v1 = Wlin[m * 64 + k + 1];
  }
  ws[i] = f16rne(v0 * sc) | (f16rne(v1 * sc) << 16);
}

#define DECLW32(wp)                                                            \
  u4 W0=(wp)[0],  W1=(wp)[1],  W2=(wp)[2],  W3=(wp)[3],                        \
     W4=(wp)[4],  W5=(wp)[5],  W6=(wp)[6],  W7=(wp)[7],                        \
     W8=(wp)[8],  W9=(wp)[9],  W10=(wp)[10],W11=(wp)[11],                      \
     W12=(wp)[12],W13=(wp)[13],W14=(wp)[14],W15=(wp)[15],                      \
     W16=(wp)[16],W17=(wp)[17],W18=(wp)[18],W19=(wp)[19],                      \
     W20=(wp)[20],W21=(wp)[21],W22=(wp)[22],W23=(wp)[23],                      \
     W24=(wp)[24],W25=(wp)[25],W26=(wp)[26],W27=(wp)[27],                      \
     W28=(wp)[28],W29=(wp)[29],W30=(wp)[30],W31=(wp)[31]

#define PINW8(a,b,c,d,e,f,g,h)                                                 \
  asm volatile("" : "+v"(a), "+v"(b), "+v"(c), "+v"(d),                        \
                    "+v"(e), "+v"(f), "+v"(g), "+v"(h))
#define PINALL() { PINW8(W0,W1,W2,W3,W4,W5,W6,W7);                             \
                   PINW8(W8,W9,W10,W11,W12,W13,W14,W15);                       \
                   PINW8(W16,W17,W18,W19,W20,W21,W22,W23);                     \
                   PINW8(W24,W25,W26,W27,W28,W29,W30,W31); }

__global__ __launch_bounds__(192)
__attribute__((amdgpu_waves_per_eu(1, 1)))
void rnn_fused(
    const float* __restrict__ y,
    const float* __restrict__ Wih0, const float* __restrict__ bih0,
    const float* __restrict__ bhh0,
    const float* __restrict__ bih1, const float* __restrict__ bhh1,
    const float* __restrict__ blin,
    const unsigned* __restrict__ ws,
    float* __restrict__ out)
{
  const int tid = threadIdx.x;
  // rings: block j occupies slots [j*B .. j*B+B) & (RS-1) — adjacent blocks
  // land in disjoint halves, so all cross-wave same-slot reuse is >= 1
  // barrier apart.
  __shared__ __align__(16) unsigned h0r[RS * 32];   // h0 f16, 8 KB
  __shared__ __align__(16) unsigned h1r[RS * 32];   // h1 f16, 8 KB
  __shared__ __align__(16) float    xpf[RS * 256];  // xp1 f32 elem-major, 64 KB

  for (int j = tid; j < RS * 32; j += 192) { h0r[j] = 0u; h1r[j] = 0u; }
  __syncthreads();

  if (tid < 64) {
    // ================= wave0: layer 0, all 4 gates per lane =================
    __builtin_amdgcn_s_setprio(1);
    const int e = tid;
    const u4* wp = (const u4*)(ws + e * 128);
    DECLW32(wp);
    float bbi = (bih0[e] + bhh0[e]) * L2E;
    float bbf = (bih0[64 + e] + bhh0[64 + e]) * L2E;
    float bbg = (bih0[128 + e] + bhh0[128 + e]) * L2E2;
    float bbo = (bih0[192 + e] + bhh0[192 + e]) * L2E;
    float wii = Wih0[e] * L2E, wif = Wih0[64 + e] * L2E;
    float wig = Wih0[128 + e] * L2E2, wio = Wih0[192 + e] * L2E;
    float c0 = 0.f;
    float ylv = y[e & (B - 1)];                       // lanes 0..31 hold y[0..31]
    _Float16* h0h = (_Float16*)h0r;

    for (int k = 0; k < K_SS; ++k) {
      if (k < NB) {
        float yln = (k + 1 < NB) ? y[(k + 1) * B + (e & (B - 1))] : 0.f;
        const int base = k * B;
        #pragma unroll 1
        for (int i = 0; i < B; ++i) {
          const int s = base + i;
          PINALL();
          float ys = __builtin_bit_cast(float,
              __builtin_amdgcn_readlane(__builtin_bit_cast(int, ylv), i));
          const u4* hp = (const u4*)(h0r + ((s - 1) & (RS - 1)) * 32);
          u4 H0=hp[0],H1=hp[1],H2=hp[2],H3=hp[3],H4=hp[4],H5=hp[5],H6=hp[6],H7=hp[7];
          float ai0=0,ai1=0, af0=0,af1=0, ag0=0,ag1=0, ao0=0,ao1=0;
          DP4(ai0,W0,H0)  DP4(af0,W8,H0)  DP4(ag0,W16,H0) DP4(ao0,W24,H0)
          DP4(ai1,W1,H1)  DP4(af1,W9,H1)  DP4(ag1,W17,H1) DP4(ao1,W25,H1)
          DP4(ai0,W2,H2)  DP4(af0,W10,H2) DP4(ag0,W18,H2) DP4(ao0,W26,H2)
          DP4(ai1,W3,H3)  DP4(af1,W11,H3) DP4(ag1,W19,H3) DP4(ao1,W27,H3)
          DP4(ai0,W4,H4)  DP4(af0,W12,H4) DP4(ag0,W20,H4) DP4(ao0,W28,H4)
          DP4(ai1,W5,H5)  DP4(af1,W13,H5) DP4(ag1,W21,H5) DP4(ao1,W29,H5)
          DP4(ai0,W6,H6)  DP4(af0,W14,H6) DP4(ag0,W22,H6) DP4(ao0,W30,H6)
          DP4(ai1,W7,H7)  DP4(af1,W15,H7) DP4(ag1,W23,H7) DP4(ao1,W31,H7)
          float I = sig_u((ai0 + ai1) + fmaf(ys, wii, bbi));
          float F = sig_u((af0 + af1) + fmaf(ys, wif, bbf));
          float G = tanh_u((ag0 + ag1) + fmaf(ys, wig, bbg));
          float O = sig_u((ao0 + ao1) + fmaf(ys, wio, bbo));
          c0 = fmaf(F, c0, I * G);
          float h = O * tanh_c(c0);
          h0h[(s & (RS - 1)) * 64 + e] = (_Float16)h;   // ds_write_b16
        }
        ylv = yln;
      }
      BARRIER();
    }
  } else if (tid < 128) {
    // ========= wave1: xp1 producer (block k-1) + head (block k-3) =========
    const int e = tid - 64;
    const u4* wp = (const u4*)(ws + 16384 + e * 128);
    DECLW32(wp);
    const u4* hwp = (const u4*)(ws + 24576 + e * 8);
    u4 HW0 = hwp[0], HW1 = hwp[1];
    float bb0 = (bih1[e] + bhh1[e]) * L2E;
    float bb1 = (bih1[64 + e] + bhh1[64 + e]) * L2E;
    float bb2 = (bih1[128 + e] + bhh1[128 + e]) * L2E2;
    float bb3 = (bih1[192 + e] + bhh1[192 + e]) * L2E;
    const int m = e >> 2, kq = e & 3;
    float bl = (kq == 0) ? blin[m] : 0.f;

    for (int k = 0; k < K_SS; ++k) {
      if (k >= 1 && k <= NB) {                         // xp1 for block k-1
        const int base = (k - 1) * B;
        #pragma unroll 1
        for (int i = 0; i < B; ++i) {
          const int t = base + i;
          const int slot = t & (RS - 1);
          PINALL();
          const u4* hp = (const u4*)(h0r + slot * 32);
          u4 H0=hp[0],H1=hp[1],H2=hp[2],H3=hp[3],H4=hp[4],H5=hp[5],H6=hp[6],H7=hp[7];
          float p0a=0,p0b=0, p1a=0,p1b=0, p2a=0,p2b=0, p3a=0,p3b=0;
          DP4(p0a,W0,H0) DP4(p1a,W8,H0)  DP4(p2a,W16,H0) DP4(p3a,W24,H0)
          DP4(p0b,W1,H1) DP4(p1b,W9,H1)  DP4(p2b,W17,H1) DP4(p3b,W25,H1)
          DP4(p0a,W2,H2) DP4(p1a,W10,H2) DP4(p2a,W18,H2) DP4(p3a,W26,H2)
          DP4(p0b,W3,H3) DP4(p1b,W11,H3) DP4(p2b,W19,H3) DP4(p3b,W27,H3)
          DP4(p0a,W4,H4) DP4(p1a,W12,H4) DP4(p2a,W20,H4) DP4(p3a,W28,H4)
          DP4(p0b,W5,H5) DP4(p1b,W13,H5) DP4(p2b,W21,H5) DP4(p3b,W29,H5)
          DP4(p0a,W6,H6) DP4(p1a,W14,H6) DP4(p2a,W22,H6) DP4(p3a,W30,H6)
          DP4(p0b,W7,H7) DP4(p1b,W15,H7) DP4(p2b,W23,H7) DP4(p3b,W31,H7)
          f4 v;
          v.x = (p0a + p0b) + bb0;
          v.y = (p1a + p1b) + bb1;
          v.z = (p2a + p2b) + bb2;
          v.w = (p3a + p3b) + bb3;
          *(f4*)(xpf + slot * 256 + e * 4) = v;        // one ds_write_b128
        }
      }
      if (k >= 3) {                                    // head for block k-3
        const int base = (k - 3) * B;
        #pragma unroll 1
        for (int i = 0; i < B; ++i) {
          const int t = base + i;
          const int slot = t & (RS - 1);
          const u4* h1p = (const u4*)(h1r + slot * 32 + kq * 8);
          u4 X0 = h1p[0], X1 = h1p[1];
          float r2 = 0.f;
          DP4(r2, HW0, X0) DP4(r2, HW1, X1)
          r2 += DPPX1(r2);
          r2 += DPPX2(r2);                             // sum over kq (quad)
          if (kq == 0) out[t * 16 + m] = r2 + bl;
        }
      }
      BARRIER();
    }
  } else {
    // ============ wave2: layer-1 recurrence (block k-2), in-lane ============
    __builtin_amdgcn_s_setprio(1);
    const int e = tid - 128;
    const u4* wp = (const u4*)(ws + 8192 + e * 128);
    DECLW32(wp);
    float c1 = 0.f;
    _Float16* h1h = (_Float16*)h1r;

    for (int k = 0; k < K_SS; ++k) {
      if (k >= 2 && k <= NB + 1) {
        const int base = (k - 2) * B;
        #pragma unroll 1
        for (int i = 0; i < B; ++i) {
          const int t = base + i;
          const int slot = t & (RS - 1);
          PINALL();
          const f4 xq = *(const f4*)(xpf + slot * 256 + e * 4);  // hoisted b128
          const u4* hp = (const u4*)(h1r + ((t - 1) & (RS - 1)) * 32);
          u4 H0=hp[0],H1=hp[1],H2=hp[2],H3=hp[3],H4=hp[4],H5=hp[5],H6=hp[6],H7=hp[7];
          float ai0=0,ai1=0, af0=0,af1=0, ag0=0,ag1=0, ao0=0,ao1=0;
          DP4(ai0,W0,H0)  DP4(af0,W8,H0)  DP4(ag0,W16,H0) DP4(ao0,W24,H0)
          DP4(ai1,W1,H1)  DP4(af1,W9,H1)  DP4(ag1,W17,H1) DP4(ao1,W25,H1)
          DP4(ai0,W2,H2)  DP4(af0,W10,H2) DP4(ag0,W18,H2) DP4(ao0,W26,H2)
          DP4(ai1,W3,H3)  DP4(af1,W11,H3) DP4(ag1,W19,H3) DP4(ao1,W27,H3)
          DP4(ai0,W4,H4)  DP4(af0,W12,H4) DP4(ag0,W20,H4) DP4(ao0,W28,H4)
          DP4(ai1,W5,H5)  DP4(af1,W13,H5) DP4(ag1,W21,H5) DP4(ao1,W29,H5)
          DP4(ai0,W6,H6)  DP4(af0,W14,H6) DP4(ag0,W22,H6) DP4(ao0,W30,H6)
          DP4(ai1,W7,H7)  DP4(af1,W15,H7) DP4(ag1,W23,H7) DP4(ao1,W31,H7)
          float I = sig_u(xq.x + (ai0 + ai1));
          float F = sig_u(xq.y + (af0 + af1));
          float G = tanh_u(xq.z + (ag0 + ag1));
          float O = sig_u(xq.w + (ao0 + ao1));
          c1 = fmaf(F, c1, I * G);
          float h = O * tanh_c(c1);
          h1h[slot * 64 + e] = (_Float16)h;            // ds_write_b16
        }
      }
      BARRIER();
    }
  }
}

extern "C" void kernel_launch(void* const* d_in, const int* in_sizes, int n_in,
                              void* d_out, int out_size, void* d_ws, size_t ws_size,
                              hipStream_t stream) {
  const float* y    = (const float*)d_in[0];
  const float* Wih0 = (const float*)d_in[1];
  const float* Whh0 = (const float*)d_in[2];
  const float* bih0 = (const float*)d_in[3];
  const float* bhh0 = (const float*)d_in[4];
  const float* Wih1 = (const float*)d_in[5];
  const float* Whh1 = (const float*)d_in[6];
  const float* bih1 = (const float*)d_in[7];
  const float* bhh1 = (const float*)d_in[8];
  const float* Wlin = (const float*)d_in[9];
  const float* blin = (const float*)d_in[10];
  unsigned* ws = (unsigned*)d_ws;                // 25088 dwords ~= 100 KB

  pack_w<<<dim3(98), dim3(256), 0, stream>>>(Whh0, Whh1, Wih1, Wlin, ws);
  rnn_fused<<<dim3(1), dim3(192), 0, stream>>>(
      y, Wih0, bih0, bhh0, bih1, bhh1, blin, ws, (float*)d_out);
}